// Round 1
// 171.365 us; speedup vs baseline: 1.0626x; 1.0626x over previous
//
#include <hip/hip_runtime.h>
#include <math.h>

#define B_    2
#define L_    2048
#define D_    1024
#define H_    16
#define HD_   64
#define HALF_ 128
#define TQ    32          // queries per attention block
#define PST   296         // bf16 P-slab row stride (shorts); 16B-aligned, bank-tiled

typedef __attribute__((ext_vector_type(8))) short short8;
typedef __attribute__((ext_vector_type(4))) float f32x4;

// ---- bf16 helpers (bitwise, RNE) -----------------------------------------
__device__ __forceinline__ unsigned short f2bf(float x) {
  unsigned int u = __float_as_uint(x);
  u = (u + 0x7fffu + ((u >> 16) & 1u)) >> 16;
  return (unsigned short)u;
}

__device__ __forceinline__ void async_cp16(const unsigned short* g, unsigned short* l) {
  __builtin_amdgcn_global_load_lds(
      (const __attribute__((address_space(1))) unsigned int*)g,
      (__attribute__((address_space(3))) unsigned int*)l, 16, 0, 0);
}

// ---------------------------------------------------------------------------
// prep: fused (a) x -> bf16 round (hi only), (b) w_qkv transpose+round,
//       (c) w_out transpose+round.
// ---------------------------------------------------------------------------
__device__ __forceinline__ void tr_round32(const float* __restrict__ in,
                                           unsigned short* __restrict__ hi,
                                           int N, int K, int n0, int k0,
                                           float (*t)[33], int tid) {
  {
    const int kl = tid >> 3, nl = (tid & 7) * 4;
    const float4 v = *(const float4*)&in[(size_t)(k0 + kl) * N + n0 + nl];
    t[kl][nl + 0] = v.x; t[kl][nl + 1] = v.y;
    t[kl][nl + 2] = v.z; t[kl][nl + 3] = v.w;
  }
  __syncthreads();
  {
    const int no = tid >> 3, ko = (tid & 7) * 4;
    ushort4 h;
    h.x = f2bf(t[ko + 0][no]);
    h.y = f2bf(t[ko + 1][no]);
    h.z = f2bf(t[ko + 2][no]);
    h.w = f2bf(t[ko + 3][no]);
    *(ushort4*)&hi[(size_t)(n0 + no) * K + k0 + ko] = h;
  }
}

__global__ __launch_bounds__(256) void prep(const float* __restrict__ x,
                                            unsigned short* __restrict__ x_hi,
                                            const float* __restrict__ w_qkv,
                                            unsigned short* __restrict__ wqkvT,
                                            const float* __restrict__ w_out,
                                            unsigned short* __restrict__ woutT) {
  __shared__ float t[32][33];
  const int bx = blockIdx.x, tid = threadIdx.x;
  if (bx < 4096) {
    const int i = (bx * 256 + tid) * 4;
    const float4 a = *(const float4*)&x[i];
    ushort4 h;
    h.x = f2bf(a.x); h.y = f2bf(a.y); h.z = f2bf(a.z); h.w = f2bf(a.w);
    *(ushort4*)&x_hi[i] = h;
  } else if (bx < 7168) {
    const int tb = bx - 4096;  // 96 x 32 tiles
    tr_round32(w_qkv, wqkvT, 3 * D_, D_, (tb % 96) * 32, (tb / 96) * 32, t, tid);
  } else {
    const int tb = bx - 7168;  // 32 x 32 tiles
    tr_round32(w_out, woutT, D_, D_, (tb % 32) * 32, (tb / 32) * 32, t, tid);
  }
}

// ---------------------------------------------------------------------------
// gemm_qkv: SINGLE-product bf16 MFMA GEMM for the FULL QKV projection
// (N = 3072 in one kernel — V columns moved up from the 128x64 structure).
// 128x128 tile, BK=32, 16 KB LDS, balanced 4-inst/wave staging, branch-free
// K-loop.  Epilogue is 3-way on wave-uniform slot = col>>10:
//   slot 0: q -> q_hi[B*L,1024]
//   slot 1: k -> kT[b][h][dg8][j2048][8d]
//   slot 2: v -> vTile[b][jg256][d1024][8j]   (ushort4 vectorized)
// Grid 24x32 = 768 blocks = 3 blocks/CU (the measured sweet spot for this
// structure), vs 512(2/CU)+512 for the old split pair.
// ---------------------------------------------------------------------------
__global__ __launch_bounds__(256) void gemm_qkv(const unsigned short* __restrict__ Ah,
                                                const unsigned short* __restrict__ Bh,
                                                const float* __restrict__ bias,
                                                unsigned short* __restrict__ q_hi,
                                                unsigned short* __restrict__ kT,
                                                unsigned short* __restrict__ vTile,
                                                int N, int K) {
  __shared__ unsigned short sm[2 * 4096];  // 16 KB: Ah | Bh
  const int tid  = threadIdx.x;
  const int wave = tid >> 6, lane = tid & 63;
  const int m0 = blockIdx.y * 128, n0 = blockIdx.x * 128;
  const int wm = (wave >> 1) * 64, wn = (wave & 1) * 64;
  const int quad = lane >> 4, ln16 = lane & 15;

  const unsigned short* src = (wave < 2) ? Ah : Bh;
  const int baserow = (wave < 2) ? m0 : n0;
  const int io = (wave & 1) * 4;
  size_t goff[4];
#pragma unroll
  for (int i = 0; i < 4; ++i) {
    const int inst = io + i;
    const int r = inst * 16 + (lane >> 2);
    const int q = (lane & 3) ^ ((r >> 1) & 3);
    goff[i] = (size_t)(baserow + r) * K + q * 8;
  }
  unsigned short* dst0 = &sm[(wave >> 1) * 4096 + io * 512];

  int offA[4], offB[4];
#pragma unroll
  for (int t = 0; t < 4; ++t) {
    const int r = wm + t * 16 + ln16;
    offA[t] = r * 64 + ((quad ^ ((r >> 1) & 3)) * 16);
    const int rn = wn + t * 16 + ln16;
    offB[t] = rn * 64 + ((quad ^ ((rn >> 1) & 3)) * 16);
  }

  f32x4 acc[4][4] = {};
  const char* smb = (const char*)sm;

  for (int k0 = 0; k0 < K; k0 += 32) {
#pragma unroll
    for (int i = 0; i < 4; ++i)
      async_cp16(src + goff[i] + k0,
                 (unsigned short*)((char*)dst0 + i * 1024));
    __syncthreads();

    short8 ah[4], bh[4];
#pragma unroll
    for (int t = 0; t < 4; ++t) {
      ah[t] = *(const short8*)(smb + offA[t]);
      bh[t] = *(const short8*)(smb + 8192 + offB[t]);
    }
#pragma unroll
    for (int t = 0; t < 4; ++t)
#pragma unroll
      for (int u = 0; u < 4; ++u)
        acc[t][u] = __builtin_amdgcn_mfma_f32_16x16x32_bf16(ah[t], bh[u], acc[t][u], 0, 0, 0);
    __syncthreads();
  }

#pragma unroll
  for (int u = 0; u < 4; ++u) {
    const int col = n0 + wn + u * 16 + ln16;
    const float bv = bias[col];
    const int slot = col >> 10;   // 0=q, 1=k, 2=v (wave-uniform per u-tile)
    const int hd   = col & 1023;
    const int hh_  = hd >> 6;
    const int dg   = (hd & 63) >> 3, di = hd & 7;
#pragma unroll
    for (int t = 0; t < 4; ++t) {
      const int row0 = m0 + wm + t * 16 + quad * 4;
      if (slot == 0) {
#pragma unroll
        for (int e = 0; e < 4; ++e)
          q_hi[(size_t)(row0 + e) * 1024 + hd] = f2bf(acc[t][u][e] + bv);
      } else if (slot == 1) {
#pragma unroll
        for (int e = 0; e < 4; ++e) {
          const int tok = row0 + e;
          const int bb = tok >> 11, j = tok & 2047;
          const size_t o =
              ((((size_t)bb * 16 + hh_) * 8 + dg) * 2048 + j) * 8 + di;
          kT[o] = f2bf(acc[t][u][e] + bv);
        }
      } else {
        const int bb = row0 >> 11, l0 = row0 & 2047;
        ushort4 vh;
        vh.x = f2bf(acc[t][u][0] + bv);
        vh.y = f2bf(acc[t][u][1] + bv);
        vh.z = f2bf(acc[t][u][2] + bv);
        vh.w = f2bf(acc[t][u][3] + bv);
        const size_t o =
            (((size_t)bb * 256 + (l0 >> 3)) * 1024 + hd) * 8 + (l0 & 7);
        *(ushort4*)&vTile[o] = vh;
      }
    }
  }
}

// ---------------------------------------------------------------------------
// gemm_n64s: SINGLE-product bf16 GEMM, 128x64 tile, BK=32, 12 KB LDS,
// 512 blocks (2/CU). Balanced 3-inst/wave staging (12 insts: Ah 8 + Bh 4),
// branch-free K-loop. EPI=0: fp32 C (out-projection, A = attn_h).
// (EPI=1 retained but no longer launched — V moved into gemm_qkv.)
// ---------------------------------------------------------------------------
template <int EPI>
__global__ __launch_bounds__(256) void gemm_n64s(const unsigned short* __restrict__ Ah,
                                                 const unsigned short* __restrict__ Bh,
                                                 const float* __restrict__ bias,
                                                 float* __restrict__ C,
                                                 unsigned short* __restrict__ vTile,
                                                 int N, int K) {
  __shared__ unsigned short sm[6144];  // 12 KB: Ah (8 KB) | Bh (4 KB)
  const int tid  = threadIdx.x;
  const int wave = tid >> 6, lane = tid & 63;
  const int m0 = blockIdx.y * 128, n0 = blockIdx.x * 64;
  const int quad = lane >> 4, ln16 = lane & 15;
  const int wm = wave * 32;

  // staging: 12 insts distributed 3/wave.  g = wave*3+s; g<8 -> Ah, else Bh.
  const unsigned short* sptr[3];
  int dstoff[3];
#pragma unroll
  for (int s = 0; s < 3; ++s) {
    const int g = wave * 3 + s;
    const bool isA = g < 8;
    const unsigned short* base = isA ? Ah : Bh;
    const int r0 = isA ? (m0 + g * 16) : (n0 + (g - 8) * 16);
    const int r = r0 + (lane >> 2);
    const int q = (lane & 3) ^ ((r >> 1) & 3);
    sptr[s] = base + (size_t)r * K + q * 8;
    dstoff[s] = isA ? g * 1024 : 8192 + (g - 8) * 1024;
  }

  int offA[2], offB[4];
#pragma unroll
  for (int t = 0; t < 2; ++t) {
    const int r = wm + t * 16 + ln16;
    offA[t] = r * 64 + ((quad ^ ((r >> 1) & 3)) * 16);
  }
#pragma unroll
  for (int u = 0; u < 4; ++u) {
    const int rn = u * 16 + ln16;
    offB[u] = rn * 64 + ((quad ^ ((rn >> 1) & 3)) * 16);
  }

  f32x4 acc[2][4] = {};
  const char* smb = (const char*)sm;

  for (int k0 = 0; k0 < K; k0 += 32) {
#pragma unroll
    for (int s = 0; s < 3; ++s)
      async_cp16(sptr[s] + k0, (unsigned short*)((char*)sm + dstoff[s]));
    __syncthreads();

    short8 ah[2], bh[4];
#pragma unroll
    for (int t = 0; t < 2; ++t) ah[t] = *(const short8*)(smb + offA[t]);
#pragma unroll
    for (int u = 0; u < 4; ++u) bh[u] = *(const short8*)(smb + 8192 + offB[u]);
#pragma unroll
    for (int t = 0; t < 2; ++t)
#pragma unroll
      for (int u = 0; u < 4; ++u)
        acc[t][u] = __builtin_amdgcn_mfma_f32_16x16x32_bf16(ah[t], bh[u], acc[t][u], 0, 0, 0);
    __syncthreads();
  }

#pragma unroll
  for (int u = 0; u < 4; ++u) {
    const int col = n0 + u * 16 + ln16;
    const float bv = bias[col];
#pragma unroll
    for (int t = 0; t < 2; ++t) {
      const int row0 = m0 + wm + t * 16 + quad * 4;
      if (EPI == 0) {
#pragma unroll
        for (int e = 0; e < 4; ++e)
          C[(size_t)(row0 + e) * N + col] = acc[t][u][e] + bv;
      } else {
        const int bb = row0 >> 11, l0 = row0 & 2047;
        ushort4 vh;
        vh.x = f2bf(acc[t][u][0] + bv);
        vh.y = f2bf(acc[t][u][1] + bv);
        vh.z = f2bf(acc[t][u][2] + bv);
        vh.w = f2bf(acc[t][u][3] + bv);
        const size_t o =
            (((size_t)bb * 256 + (l0 >> 3)) * 1024 + col) * 8 + (l0 & 7);
        *(ushort4*)&vTile[o] = vh;
      }
    }
  }
}

// ---------------------------------------------------------------------------
// MFMA sliding-window attention (r11 structure; epilogue writes attn_h only —
// the out-projection is single-product, attn_lo is dead).
// ---------------------------------------------------------------------------
__global__ __launch_bounds__(256, 4) void attn_mfma(
    const unsigned short* __restrict__ q_hi,
    const unsigned short* __restrict__ kT,
    const unsigned short* __restrict__ vTile,
    unsigned short* __restrict__ attn_h) {
  __shared__ unsigned short P[TQ * PST];  // 18944 B (epilogue reuses as fp32)
  __shared__ float redS[2][32];

  const int b   = blockIdx.z;
  const int h   = blockIdx.y;
  const int i0  = blockIdx.x * TQ;
  const int tid = threadIdx.x;
  const int wave = tid >> 6, lane = tid & 63;
  const int quad = lane >> 4, ln16 = lane & 15;
  const int mt = wave >> 1, np = wave & 1;
  const int jlo = i0 - HALF_;
  const int rbase = mt * 16 + quad * 4;

  // ---- phase 1: scores -> exp -> P(bf16, unnormalized) + row sums --------
  float s[4] = {0.f, 0.f, 0.f, 0.f};
  {
    const size_t qbase =
        (size_t)(b * L_ + i0 + mt * 16 + ln16) * 1024 + h * 64 + quad * 8;
    const short8 qh0 = *(const short8*)&q_hi[qbase];
    const short8 qh1 = *(const short8*)&q_hi[qbase + 32];

    const size_t kb0 = (((size_t)b * 16 + h) * 8 + quad) * 2048 * 8;
    const size_t kb1 = (((size_t)b * 16 + h) * 8 + quad + 4) * 2048 * 8;

#pragma unroll
    for (int c = 0; c < 9; ++c) {
      const int nt   = np + 2 * c;
      const int jabs = jlo + nt * 16 + ln16;
      const int jcl  = min(max(jabs, 0), L_ - 1);
      const short8 kh0 = *(const short8*)&kT[kb0 + (size_t)jcl * 8];
      const short8 kh1 = *(const short8*)&kT[kb1 + (size_t)jcl * 8];

      f32x4 a = {};
      a = __builtin_amdgcn_mfma_f32_16x16x32_bf16(qh0, kh0, a, 0, 0, 0);
      a = __builtin_amdgcn_mfma_f32_16x16x32_bf16(qh1, kh1, a, 0, 0, 0);

      const int colj = nt * 16 + ln16;
#pragma unroll
      for (int e = 0; e < 4; ++e) {
        const int iabs = i0 + rbase + e;
        const bool ok = (jabs >= 0) && (jabs < L_) && (abs(iabs - jabs) <= HALF_);
        const float ev = ok ? __expf(a[e] * 0.125f) : 0.f;
        s[e] += ev;
        P[(rbase + e) * PST + colj] = f2bf(ev);
      }
    }
  }
#pragma unroll
  for (int e = 0; e < 4; ++e) {
    s[e] += __shfl_xor(s[e], 1);
    s[e] += __shfl_xor(s[e], 2);
    s[e] += __shfl_xor(s[e], 4);
    s[e] += __shfl_xor(s[e], 8);
  }
  if (ln16 == 0) {
#pragma unroll
    for (int e = 0; e < 4; ++e) redS[np][rbase + e] = s[e];
  }
  __syncthreads();
  float rinv[4];
#pragma unroll
  for (int e = 0; e < 4; ++e) rinv[e] = 1.f / (s[e] + redS[np ^ 1][rbase + e]);

  // ---- phase 2: O = P @ Vh (frag-tiled vTile, coalesced) ------------------
  f32x4 o[2] = {};
  {
    const int dp = np;
    const char* pb = (const char*)P;
#pragma unroll
    for (int c = 0; c < 9; ++c) {
      const short8 pf =
          *(const short8*)(pb + (mt * 16 + ln16) * (PST * 2) + c * 64 + quad * 16);
      int j0 = jlo + c * 32 + quad * 8;
      j0 = min(max(j0, 0), L_ - 8);
      const size_t jgbase = ((size_t)b * 256 + (j0 >> 3)) * 1024;
#pragma unroll
      for (int t = 0; t < 2; ++t) {
        const size_t vb = (jgbase + (h * 64 + dp * 32 + t * 16 + ln16)) * 8;
        const short8 vh = *(const short8*)&vTile[vb];
        o[t] = __builtin_amdgcn_mfma_f32_16x16x32_bf16(pf, vh, o[t], 0, 0, 0);
      }
    }
  }

  // ---- epilogue: normalize, LDS bounce, coalesced bf16 stores ------------
  __syncthreads();
  float* ob = (float*)P;
  {
    const int dp = np;
#pragma unroll
    for (int t = 0; t < 2; ++t)
#pragma unroll
      for (int e = 0; e < 4; ++e)
        ob[(rbase + e) * 68 + dp * 32 + t * 16 + ln16] = o[t][e] * rinv[e];
  }
  __syncthreads();
  {
    const int rr = tid >> 3, ck = tid & 7;
    const float* rp = ob + rr * 68 + ck * 8;
    const float4 f0 = *(const float4*)&rp[0];
    const float4 f1 = *(const float4*)&rp[4];
    short8 hh;
    hh[0] = (short)f2bf(f0.x); hh[1] = (short)f2bf(f0.y);
    hh[2] = (short)f2bf(f0.z); hh[3] = (short)f2bf(f0.w);
    hh[4] = (short)f2bf(f1.x); hh[5] = (short)f2bf(f1.y);
    hh[6] = (short)f2bf(f1.z); hh[7] = (short)f2bf(f1.w);
    const size_t oo = ((size_t)(b * L_ + i0 + rr)) * 1024 + h * 64 + ck * 8;
    *(short8*)&attn_h[oo] = hh;
  }
}

// ---------------------------------------------------------------------------
extern "C" void kernel_launch(void* const* d_in, const int* in_sizes, int n_in,
                              void* d_out, int out_size, void* d_ws, size_t ws_size,
                              hipStream_t stream) {
  const float* x     = (const float*)d_in[0];
  const float* w_qkv = (const float*)d_in[1];
  const float* b_qkv = (const float*)d_in[2];
  const float* w_out = (const float*)d_in[3];
  const float* b_out = (const float*)d_in[4];
  float* out = (float*)d_out;

  const int M = B_ * L_;  // 4096

  // workspace layout (bytes), total 48 MiB:
  //   x_hi @0 (8MiB)        [dead after QKV gemm; attn_h aliases it]
  //   wqkvT @16MiB (6MiB)
  //   woutT @22MiB (2MiB)
  //   q_hi  @24MiB (8MiB)   [B*L, 1024]
  //   kT    @32MiB (8MiB)   [b][h][dg8][j2048][8d]
  //   vTile @40MiB (8MiB)   [b][jg256][d1024][8j]
  char* ws = (char*)d_ws;
  unsigned short* x_hi    = (unsigned short*)(ws + 0);
  unsigned short* wqkvT   = (unsigned short*)(ws + 16777216);
  unsigned short* woutT   = (unsigned short*)(ws + 23068672);
  unsigned short* q_hi    = (unsigned short*)(ws + 25165824);
  unsigned short* kT      = (unsigned short*)(ws + 33554432);
  unsigned short* vTile   = (unsigned short*)(ws + 41943040);
  unsigned short* attn_hi = (unsigned short*)(ws + 0);

  // 1) fused prep: x round + both weight transposes
  prep<<<8192, 256, 0, stream>>>(x, x_hi, w_qkv, wqkvT, w_out, woutT);
  // 2) fused QKV projection (single-product, 128x128) -> q_hi + kT + vTile
  {
    dim3 g(3072 / 128, M / 128);  // 24 x 32 = 768 blocks = 3/CU
    gemm_qkv<<<g, 256, 0, stream>>>(x_hi, wqkvT, b_qkv, q_hi, kT, vTile,
                                    3072, D_);
  }
  // 3) MFMA banded attention -> attn_h bf16 (aliases dead x_hi)
  {
    dim3 g(L_ / TQ, H_, B_);
    attn_mfma<<<g, 256, 0, stream>>>(q_hi, kT, vTile, attn_hi);
  }
  // 4) output projection (single-product) -> fp32 d_out
  {
    dim3 g(D_ / 64, M / 128);
    gemm_n64s<0><<<g, 256, 0, stream>>>(attn_hi, woutT, b_out, out,
                                        nullptr, D_, D_);
  }
}

// Round 2
// 161.655 us; speedup vs baseline: 1.1264x; 1.0601x over previous
//
#include <hip/hip_runtime.h>
#include <math.h>

#define B_    2
#define L_    2048
#define D_    1024
#define H_    16
#define HD_   64
#define HALF_ 128
#define TQ    32          // queries per attention block
#define PST   296         // bf16 P-slab row stride (shorts); 16B-aligned, bank-tiled

typedef __attribute__((ext_vector_type(8))) short short8;
typedef __attribute__((ext_vector_type(4))) float f32x4;

// ---- bf16 helpers (bitwise, RNE) -----------------------------------------
__device__ __forceinline__ unsigned short f2bf(float x) {
  unsigned int u = __float_as_uint(x);
  u = (u + 0x7fffu + ((u >> 16) & 1u)) >> 16;
  return (unsigned short)u;
}

__device__ __forceinline__ void async_cp16(const unsigned short* g, unsigned short* l) {
  __builtin_amdgcn_global_load_lds(
      (const __attribute__((address_space(1))) unsigned int*)g,
      (__attribute__((address_space(3))) unsigned int*)l, 16, 0, 0);
}

// ---------------------------------------------------------------------------
// prep: fused (a) x -> bf16 round (hi only), (b) w_qkv transpose+round,
//       (c) w_out transpose+round.
// ---------------------------------------------------------------------------
__device__ __forceinline__ void tr_round32(const float* __restrict__ in,
                                           unsigned short* __restrict__ hi,
                                           int N, int K, int n0, int k0,
                                           float (*t)[33], int tid) {
  {
    const int kl = tid >> 3, nl = (tid & 7) * 4;
    const float4 v = *(const float4*)&in[(size_t)(k0 + kl) * N + n0 + nl];
    t[kl][nl + 0] = v.x; t[kl][nl + 1] = v.y;
    t[kl][nl + 2] = v.z; t[kl][nl + 3] = v.w;
  }
  __syncthreads();
  {
    const int no = tid >> 3, ko = (tid & 7) * 4;
    ushort4 h;
    h.x = f2bf(t[ko + 0][no]);
    h.y = f2bf(t[ko + 1][no]);
    h.z = f2bf(t[ko + 2][no]);
    h.w = f2bf(t[ko + 3][no]);
    *(ushort4*)&hi[(size_t)(n0 + no) * K + k0 + ko] = h;
  }
}

__global__ __launch_bounds__(256) void prep(const float* __restrict__ x,
                                            unsigned short* __restrict__ x_hi,
                                            const float* __restrict__ w_qkv,
                                            unsigned short* __restrict__ wqkvT,
                                            const float* __restrict__ w_out,
                                            unsigned short* __restrict__ woutT) {
  __shared__ float t[32][33];
  const int bx = blockIdx.x, tid = threadIdx.x;
  if (bx < 4096) {
    const int i = (bx * 256 + tid) * 4;
    const float4 a = *(const float4*)&x[i];
    ushort4 h;
    h.x = f2bf(a.x); h.y = f2bf(a.y); h.z = f2bf(a.z); h.w = f2bf(a.w);
    *(ushort4*)&x_hi[i] = h;
  } else if (bx < 7168) {
    const int tb = bx - 4096;  // 96 x 32 tiles
    tr_round32(w_qkv, wqkvT, 3 * D_, D_, (tb % 96) * 32, (tb / 96) * 32, t, tid);
  } else {
    const int tb = bx - 7168;  // 32 x 32 tiles
    tr_round32(w_out, woutT, D_, D_, (tb % 32) * 32, (tb / 32) * 32, t, tid);
  }
}

// ---------------------------------------------------------------------------
// gemm_qkv: fused QKV projection, 128x128 tile, BK=64 (16 K-steps), 32 KB
// staging LDS, zero-conflict chunk^=(r&7) swizzle for 128-B rows.
// SWAPPED MFMA operands: acc[t][u] = mfma(bh[u], ah[t], .) so the D-frag
// reg-index dim is the n (hd) axis -> vectorized ushort4 epilogue stores
// (no read-for-ownership from 2-B scalars).  V-slot bounces through the
// staging LDS for token-minor layout with fully coalesced 16-B stores.
// Grid: 768 blocks (3/CU), bijective XCD swizzle (768 % 8 == 0).
// ---------------------------------------------------------------------------
__global__ __launch_bounds__(256, 3) void gemm_qkv(
    const unsigned short* __restrict__ Ah,
    const unsigned short* __restrict__ Bh,
    const float* __restrict__ bias,
    unsigned short* __restrict__ q_hi,
    unsigned short* __restrict__ kT,
    unsigned short* __restrict__ vTile,
    int N, int K) {
  // staging: A [128][64] bf16 (16 KB) | B [128][64] bf16 (16 KB) = 32 KB.
  // v-epilogue bounce reuses this as [128][132] ushort (33792 B).
  __shared__ char smraw[33792];
  const int tid  = threadIdx.x;
  const int wave = tid >> 6, lane = tid & 63;

  // bijective XCD swizzle: lin -> (lin%8)*96 + lin/8  (nwg=768, 768%8==0)
  const int lin = blockIdx.y * gridDim.x + blockIdx.x;
  const int swz = (lin & 7) * 96 + (lin >> 3);
  const int n0 = (swz % 24) * 128, m0 = (swz / 24) * 128;

  const int wm = (wave >> 1) * 64, wn = (wave & 1) * 64;
  const int quad = lane >> 4, ln16 = lane & 15;

  // ---- staging addresses: 32 insts total, 8 per wave -----------------------
  // waves 0,1 -> A rows 0-63 / 64-127 ; waves 2,3 -> B rows 0-63 / 64-127
  const bool isA = wave < 2;
  const unsigned short* src = isA ? Ah : Bh;
  const int baserow = isA ? m0 : n0;
  const int instbase = (wave & 1) * 8;
  const int dbase = (isA ? 0 : 16384) + instbase * 1024;  // bytes
  size_t goff[8];
#pragma unroll
  for (int i = 0; i < 8; ++i) {
    const int r = (instbase + i) * 8 + (lane >> 3);   // row within tile 0..127
    const int c = (lane & 7) ^ (r & 7);               // source k-chunk (involution)
    goff[i] = (size_t)(baserow + r) * K + c * 8;
  }

  // ---- ds_read offsets (bytes), chunk^=(r&7) swizzle, ks=1 is ^64 ---------
  int offA[4], offB[4];
#pragma unroll
  for (int t = 0; t < 4; ++t) {
    const int r = wm + t * 16 + ln16;
    offA[t] = r * 128 + ((quad ^ (r & 7)) * 16);
    const int rn = wn + t * 16 + ln16;
    offB[t] = 16384 + rn * 128 + ((quad ^ (rn & 7)) * 16);
  }

  f32x4 acc[4][4] = {};
  const char* smb = (const char*)smraw;

  for (int k0 = 0; k0 < K; k0 += 64) {
#pragma unroll
    for (int i = 0; i < 8; ++i)
      async_cp16(src + goff[i] + k0,
                 (unsigned short*)(smraw + dbase + i * 1024));
    __syncthreads();

    // ks = 0 (k 0..31)
    {
      short8 ah[4], bh[4];
#pragma unroll
      for (int t = 0; t < 4; ++t) {
        ah[t] = *(const short8*)(smb + offA[t]);
        bh[t] = *(const short8*)(smb + offB[t]);
      }
#pragma unroll
      for (int t = 0; t < 4; ++t)
#pragma unroll
        for (int u = 0; u < 4; ++u)
          acc[t][u] = __builtin_amdgcn_mfma_f32_16x16x32_bf16(bh[u], ah[t], acc[t][u], 0, 0, 0);
    }
    // ks = 1 (k 32..63): swizzled position differs by ^64 bytes
    {
      short8 ah[4], bh[4];
#pragma unroll
      for (int t = 0; t < 4; ++t) {
        ah[t] = *(const short8*)(smb + (offA[t] ^ 64));
        bh[t] = *(const short8*)(smb + (offB[t] ^ 64));
      }
#pragma unroll
      for (int t = 0; t < 4; ++t)
#pragma unroll
        for (int u = 0; u < 4; ++u)
          acc[t][u] = __builtin_amdgcn_mfma_f32_16x16x32_bf16(bh[u], ah[t], acc[t][u], 0, 0, 0);
    }
    __syncthreads();
  }

  // ---- epilogue. Swapped-D mapping: m = wm+t*16+ln16 ; n = wn+u*16+quad*4+e
  const int slot = n0 >> 10;       // block-uniform: 0=q, 1=k, 2=v
  const int nbase = n0 & 1023;

  if (slot == 0) {
#pragma unroll
    for (int t = 0; t < 4; ++t) {
      const int m = m0 + wm + t * 16 + ln16;
#pragma unroll
      for (int u = 0; u < 4; ++u) {
        const int nl = wn + u * 16 + quad * 4;
        const float4 bq = *(const float4*)&bias[n0 + nl];
        ushort4 h;
        h.x = f2bf(acc[t][u][0] + bq.x);
        h.y = f2bf(acc[t][u][1] + bq.y);
        h.z = f2bf(acc[t][u][2] + bq.z);
        h.w = f2bf(acc[t][u][3] + bq.w);
        *(ushort4*)&q_hi[(size_t)m * 1024 + nbase + nl] = h;
      }
    }
  } else if (slot == 1) {
#pragma unroll
    for (int t = 0; t < 4; ++t) {
      const int tok = m0 + wm + t * 16 + ln16;
      const int bb = tok >> 11, j = tok & 2047;
#pragma unroll
      for (int u = 0; u < 4; ++u) {
        const int nl = wn + u * 16 + quad * 4;
        const float4 bq = *(const float4*)&bias[n0 + nl];
        const int hd = nbase + nl;
        const int hh_ = hd >> 6, dg = (hd & 63) >> 3, di = hd & 7;
        ushort4 h;
        h.x = f2bf(acc[t][u][0] + bq.x);
        h.y = f2bf(acc[t][u][1] + bq.y);
        h.z = f2bf(acc[t][u][2] + bq.z);
        h.w = f2bf(acc[t][u][3] + bq.w);
        const size_t o =
            ((((size_t)bb * 16 + hh_) * 8 + dg) * 2048 + j) * 8 + di;
        *(ushort4*)&kT[o] = h;
      }
    }
  } else {
    // v: bounce through LDS [128 m][132] ushort, then coalesced 16-B stores
    unsigned short* lt = (unsigned short*)smraw;
#pragma unroll
    for (int t = 0; t < 4; ++t) {
      const int ml = wm + t * 16 + ln16;
#pragma unroll
      for (int u = 0; u < 4; ++u) {
        const int nl = wn + u * 16 + quad * 4;
        const float4 bq = *(const float4*)&bias[n0 + nl];
        ushort4 h;
        h.x = f2bf(acc[t][u][0] + bq.x);
        h.y = f2bf(acc[t][u][1] + bq.y);
        h.z = f2bf(acc[t][u][2] + bq.z);
        h.w = f2bf(acc[t][u][3] + bq.w);
        *(ushort4*)&lt[ml * 132 + nl] = h;
      }
    }
    __syncthreads();
    // 128 rows x 128 cols -> vTile[b][jg][col][8j]; 2048 chunks of 8 tokens
    const int jg0 = (m0 & 2047) >> 3;
    const int bb = m0 >> 11;
#pragma unroll
    for (int it = 0; it < 8; ++it) {
      const int chunk = it * 256 + tid;
      const int hd = chunk & 127, tokg = chunk >> 7;
      short8 hh;
#pragma unroll
      for (int s = 0; s < 8; ++s)
        hh[s] = (short)lt[(tokg * 8 + s) * 132 + hd];
      const size_t o =
          (((size_t)bb * 256 + jg0 + tokg) * 1024 + nbase + hd) * 8;
      *(short8*)&vTile[o] = hh;
    }
  }
}

// ---------------------------------------------------------------------------
// gemm_n64s: SINGLE-product bf16 GEMM, 128x64 tile, BK=32, 12 KB LDS,
// 512 blocks (2/CU). EPI=0: fp32 C (out-projection, A = attn_h).
// ---------------------------------------------------------------------------
template <int EPI>
__global__ __launch_bounds__(256) void gemm_n64s(const unsigned short* __restrict__ Ah,
                                                 const unsigned short* __restrict__ Bh,
                                                 const float* __restrict__ bias,
                                                 float* __restrict__ C,
                                                 unsigned short* __restrict__ vTile,
                                                 int N, int K) {
  __shared__ unsigned short sm[6144];  // 12 KB: Ah (8 KB) | Bh (4 KB)
  const int tid  = threadIdx.x;
  const int wave = tid >> 6, lane = tid & 63;
  const int m0 = blockIdx.y * 128, n0 = blockIdx.x * 64;
  const int quad = lane >> 4, ln16 = lane & 15;
  const int wm = wave * 32;

  const unsigned short* sptr[3];
  int dstoff[3];
#pragma unroll
  for (int s = 0; s < 3; ++s) {
    const int g = wave * 3 + s;
    const bool isA = g < 8;
    const unsigned short* base = isA ? Ah : Bh;
    const int r0 = isA ? (m0 + g * 16) : (n0 + (g - 8) * 16);
    const int r = r0 + (lane >> 2);
    const int q = (lane & 3) ^ ((r >> 1) & 3);
    sptr[s] = base + (size_t)r * K + q * 8;
    dstoff[s] = isA ? g * 1024 : 8192 + (g - 8) * 1024;
  }

  int offA[2], offB[4];
#pragma unroll
  for (int t = 0; t < 2; ++t) {
    const int r = wm + t * 16 + ln16;
    offA[t] = r * 64 + ((quad ^ ((r >> 1) & 3)) * 16);
  }
#pragma unroll
  for (int u = 0; u < 4; ++u) {
    const int rn = u * 16 + ln16;
    offB[u] = rn * 64 + ((quad ^ ((rn >> 1) & 3)) * 16);
  }

  f32x4 acc[2][4] = {};
  const char* smb = (const char*)sm;

  for (int k0 = 0; k0 < K; k0 += 32) {
#pragma unroll
    for (int s = 0; s < 3; ++s)
      async_cp16(sptr[s] + k0, (unsigned short*)((char*)sm + dstoff[s]));
    __syncthreads();

    short8 ah[2], bh[4];
#pragma unroll
    for (int t = 0; t < 2; ++t) ah[t] = *(const short8*)(smb + offA[t]);
#pragma unroll
    for (int u = 0; u < 4; ++u) bh[u] = *(const short8*)(smb + 8192 + offB[u]);
#pragma unroll
    for (int t = 0; t < 2; ++t)
#pragma unroll
      for (int u = 0; u < 4; ++u)
        acc[t][u] = __builtin_amdgcn_mfma_f32_16x16x32_bf16(ah[t], bh[u], acc[t][u], 0, 0, 0);
    __syncthreads();
  }

#pragma unroll
  for (int u = 0; u < 4; ++u) {
    const int col = n0 + u * 16 + ln16;
    const float bv = bias[col];
#pragma unroll
    for (int t = 0; t < 2; ++t) {
      const int row0 = m0 + wm + t * 16 + quad * 4;
      if (EPI == 0) {
#pragma unroll
        for (int e = 0; e < 4; ++e)
          C[(size_t)(row0 + e) * N + col] = acc[t][u][e] + bv;
      } else {
        const int bb = row0 >> 11, l0 = row0 & 2047;
        ushort4 vh;
        vh.x = f2bf(acc[t][u][0] + bv);
        vh.y = f2bf(acc[t][u][1] + bv);
        vh.z = f2bf(acc[t][u][2] + bv);
        vh.w = f2bf(acc[t][u][3] + bv);
        const size_t o =
            (((size_t)bb * 256 + (l0 >> 3)) * 1024 + col) * 8 + (l0 & 7);
        *(ushort4*)&vTile[o] = vh;
      }
    }
  }
}

// ---------------------------------------------------------------------------
// MFMA sliding-window attention (unchanged).
// ---------------------------------------------------------------------------
__global__ __launch_bounds__(256, 4) void attn_mfma(
    const unsigned short* __restrict__ q_hi,
    const unsigned short* __restrict__ kT,
    const unsigned short* __restrict__ vTile,
    unsigned short* __restrict__ attn_h) {
  __shared__ unsigned short P[TQ * PST];  // 18944 B (epilogue reuses as fp32)
  __shared__ float redS[2][32];

  const int b   = blockIdx.z;
  const int h   = blockIdx.y;
  const int i0  = blockIdx.x * TQ;
  const int tid = threadIdx.x;
  const int wave = tid >> 6, lane = tid & 63;
  const int quad = lane >> 4, ln16 = lane & 15;
  const int mt = wave >> 1, np = wave & 1;
  const int jlo = i0 - HALF_;
  const int rbase = mt * 16 + quad * 4;

  // ---- phase 1: scores -> exp -> P(bf16, unnormalized) + row sums --------
  float s[4] = {0.f, 0.f, 0.f, 0.f};
  {
    const size_t qbase =
        (size_t)(b * L_ + i0 + mt * 16 + ln16) * 1024 + h * 64 + quad * 8;
    const short8 qh0 = *(const short8*)&q_hi[qbase];
    const short8 qh1 = *(const short8*)&q_hi[qbase + 32];

    const size_t kb0 = (((size_t)b * 16 + h) * 8 + quad) * 2048 * 8;
    const size_t kb1 = (((size_t)b * 16 + h) * 8 + quad + 4) * 2048 * 8;

#pragma unroll
    for (int c = 0; c < 9; ++c) {
      const int nt   = np + 2 * c;
      const int jabs = jlo + nt * 16 + ln16;
      const int jcl  = min(max(jabs, 0), L_ - 1);
      const short8 kh0 = *(const short8*)&kT[kb0 + (size_t)jcl * 8];
      const short8 kh1 = *(const short8*)&kT[kb1 + (size_t)jcl * 8];

      f32x4 a = {};
      a = __builtin_amdgcn_mfma_f32_16x16x32_bf16(qh0, kh0, a, 0, 0, 0);
      a = __builtin_amdgcn_mfma_f32_16x16x32_bf16(qh1, kh1, a, 0, 0, 0);

      const int colj = nt * 16 + ln16;
#pragma unroll
      for (int e = 0; e < 4; ++e) {
        const int iabs = i0 + rbase + e;
        const bool ok = (jabs >= 0) && (jabs < L_) && (abs(iabs - jabs) <= HALF_);
        const float ev = ok ? __expf(a[e] * 0.125f) : 0.f;
        s[e] += ev;
        P[(rbase + e) * PST + colj] = f2bf(ev);
      }
    }
  }
#pragma unroll
  for (int e = 0; e < 4; ++e) {
    s[e] += __shfl_xor(s[e], 1);
    s[e] += __shfl_xor(s[e], 2);
    s[e] += __shfl_xor(s[e], 4);
    s[e] += __shfl_xor(s[e], 8);
  }
  if (ln16 == 0) {
#pragma unroll
    for (int e = 0; e < 4; ++e) redS[np][rbase + e] = s[e];
  }
  __syncthreads();
  float rinv[4];
#pragma unroll
  for (int e = 0; e < 4; ++e) rinv[e] = 1.f / (s[e] + redS[np ^ 1][rbase + e]);

  // ---- phase 2: O = P @ Vh (frag-tiled vTile, coalesced) ------------------
  f32x4 o[2] = {};
  {
    const int dp = np;
    const char* pb = (const char*)P;
#pragma unroll
    for (int c = 0; c < 9; ++c) {
      const short8 pf =
          *(const short8*)(pb + (mt * 16 + ln16) * (PST * 2) + c * 64 + quad * 16);
      int j0 = jlo + c * 32 + quad * 8;
      j0 = min(max(j0, 0), L_ - 8);
      const size_t jgbase = ((size_t)b * 256 + (j0 >> 3)) * 1024;
#pragma unroll
      for (int t = 0; t < 2; ++t) {
        const size_t vb = (jgbase + (h * 64 + dp * 32 + t * 16 + ln16)) * 8;
        const short8 vh = *(const short8*)&vTile[vb];
        o[t] = __builtin_amdgcn_mfma_f32_16x16x32_bf16(pf, vh, o[t], 0, 0, 0);
      }
    }
  }

  // ---- epilogue: normalize, LDS bounce, coalesced bf16 stores ------------
  __syncthreads();
  float* ob = (float*)P;
  {
    const int dp = np;
#pragma unroll
    for (int t = 0; t < 2; ++t)
#pragma unroll
      for (int e = 0; e < 4; ++e)
        ob[(rbase + e) * 68 + dp * 32 + t * 16 + ln16] = o[t][e] * rinv[e];
  }
  __syncthreads();
  {
    const int rr = tid >> 3, ck = tid & 7;
    const float* rp = ob + rr * 68 + ck * 8;
    const float4 f0 = *(const float4*)&rp[0];
    const float4 f1 = *(const float4*)&rp[4];
    short8 hh;
    hh[0] = (short)f2bf(f0.x); hh[1] = (short)f2bf(f0.y);
    hh[2] = (short)f2bf(f0.z); hh[3] = (short)f2bf(f0.w);
    hh[4] = (short)f2bf(f1.x); hh[5] = (short)f2bf(f1.y);
    hh[6] = (short)f2bf(f1.z); hh[7] = (short)f2bf(f1.w);
    const size_t oo = ((size_t)(b * L_ + i0 + rr)) * 1024 + h * 64 + ck * 8;
    *(short8*)&attn_h[oo] = hh;
  }
}

// ---------------------------------------------------------------------------
extern "C" void kernel_launch(void* const* d_in, const int* in_sizes, int n_in,
                              void* d_out, int out_size, void* d_ws, size_t ws_size,
                              hipStream_t stream) {
  const float* x     = (const float*)d_in[0];
  const float* w_qkv = (const float*)d_in[1];
  const float* b_qkv = (const float*)d_in[2];
  const float* w_out = (const float*)d_in[3];
  const float* b_out = (const float*)d_in[4];
  float* out = (float*)d_out;

  const int M = B_ * L_;  // 4096

  // workspace layout (bytes), total 48 MiB:
  //   x_hi @0 (8MiB)        [dead after QKV gemm; attn_h aliases it]
  //   wqkvT @16MiB (6MiB)
  //   woutT @22MiB (2MiB)
  //   q_hi  @24MiB (8MiB)   [B*L, 1024]
  //   kT    @32MiB (8MiB)   [b][h][dg8][j2048][8d]
  //   vTile @40MiB (8MiB)   [b][jg256][d1024][8j]
  char* ws = (char*)d_ws;
  unsigned short* x_hi    = (unsigned short*)(ws + 0);
  unsigned short* wqkvT   = (unsigned short*)(ws + 16777216);
  unsigned short* woutT   = (unsigned short*)(ws + 23068672);
  unsigned short* q_hi    = (unsigned short*)(ws + 25165824);
  unsigned short* kT      = (unsigned short*)(ws + 33554432);
  unsigned short* vTile   = (unsigned short*)(ws + 41943040);
  unsigned short* attn_hi = (unsigned short*)(ws + 0);

  // 1) fused prep: x round + both weight transposes
  prep<<<8192, 256, 0, stream>>>(x, x_hi, w_qkv, wqkvT, w_out, woutT);
  // 2) fused QKV projection (BK=64, swapped-operand epilogue) -> q_hi/kT/vTile
  {
    dim3 g(3072 / 128, M / 128);  // 24 x 32 = 768 blocks = 3/CU
    gemm_qkv<<<g, 256, 0, stream>>>(x_hi, wqkvT, b_qkv, q_hi, kT, vTile,
                                    3072, D_);
  }
  // 3) MFMA banded attention -> attn_h bf16 (aliases dead x_hi)
  {
    dim3 g(L_ / TQ, H_, B_);
    attn_mfma<<<g, 256, 0, stream>>>(q_hi, kT, vTile, attn_hi);
  }
  // 4) output projection (single-product) -> fp32 d_out
  {
    dim3 g(D_ / 64, M / 128);
    gemm_n64s<0><<<g, 256, 0, stream>>>(attn_hi, woutT, b_out, out,
                                        nullptr, D_, D_);
  }
}

// Round 3
// 158.787 us; speedup vs baseline: 1.1468x; 1.0181x over previous
//
#include <hip/hip_runtime.h>
#include <math.h>

#define B_    2
#define L_    2048
#define D_    1024
#define H_    16
#define HD_   64
#define HALF_ 128
#define TQ    32          // queries per attention block
#define PST   296         // bf16 P-slab row stride (shorts); 16B-aligned, bank-tiled

typedef __attribute__((ext_vector_type(8))) short short8;
typedef __attribute__((ext_vector_type(4))) float f32x4;

// ---- bf16 helpers (bitwise, RNE) -----------------------------------------
__device__ __forceinline__ unsigned short f2bf(float x) {
  unsigned int u = __float_as_uint(x);
  u = (u + 0x7fffu + ((u >> 16) & 1u)) >> 16;
  return (unsigned short)u;
}

__device__ __forceinline__ void async_cp16(const unsigned short* g, unsigned short* l) {
  __builtin_amdgcn_global_load_lds(
      (const __attribute__((address_space(1))) unsigned int*)g,
      (__attribute__((address_space(3))) unsigned int*)l, 16, 0, 0);
}

// ---------------------------------------------------------------------------
// prep: fused (a) x -> bf16 round (hi only), (b) w_qkv transpose+round,
//       (c) w_out transpose+round.
// ---------------------------------------------------------------------------
__device__ __forceinline__ void tr_round32(const float* __restrict__ in,
                                           unsigned short* __restrict__ hi,
                                           int N, int K, int n0, int k0,
                                           float (*t)[33], int tid) {
  {
    const int kl = tid >> 3, nl = (tid & 7) * 4;
    const float4 v = *(const float4*)&in[(size_t)(k0 + kl) * N + n0 + nl];
    t[kl][nl + 0] = v.x; t[kl][nl + 1] = v.y;
    t[kl][nl + 2] = v.z; t[kl][nl + 3] = v.w;
  }
  __syncthreads();
  {
    const int no = tid >> 3, ko = (tid & 7) * 4;
    ushort4 h;
    h.x = f2bf(t[ko + 0][no]);
    h.y = f2bf(t[ko + 1][no]);
    h.z = f2bf(t[ko + 2][no]);
    h.w = f2bf(t[ko + 3][no]);
    *(ushort4*)&hi[(size_t)(n0 + no) * K + k0 + ko] = h;
  }
}

__global__ __launch_bounds__(256) void prep(const float* __restrict__ x,
                                            unsigned short* __restrict__ x_hi,
                                            const float* __restrict__ w_qkv,
                                            unsigned short* __restrict__ wqkvT,
                                            const float* __restrict__ w_out,
                                            unsigned short* __restrict__ woutT) {
  __shared__ float t[32][33];
  const int bx = blockIdx.x, tid = threadIdx.x;
  if (bx < 4096) {
    const int i = (bx * 256 + tid) * 4;
    const float4 a = *(const float4*)&x[i];
    ushort4 h;
    h.x = f2bf(a.x); h.y = f2bf(a.y); h.z = f2bf(a.z); h.w = f2bf(a.w);
    *(ushort4*)&x_hi[i] = h;
  } else if (bx < 7168) {
    const int tb = bx - 4096;  // 96 x 32 tiles
    tr_round32(w_qkv, wqkvT, 3 * D_, D_, (tb % 96) * 32, (tb / 96) * 32, t, tid);
  } else {
    const int tb = bx - 7168;  // 32 x 32 tiles
    tr_round32(w_out, woutT, D_, D_, (tb % 32) * 32, (tb / 32) * 32, t, tid);
  }
}

// ---------------------------------------------------------------------------
// gemm_qkv: fused QKV projection, 128x128 tile, BK=64 (16 K-steps), 32 KB
// staging LDS, zero-conflict chunk^=(r&7) swizzle for 128-B rows.
// SWAPPED MFMA operands: acc[t][u] = mfma(bh[u], ah[t], .) so the D-frag
// reg-index dim is the n (hd) axis -> vectorized ushort4 epilogue stores.
// Grid: 768 blocks (3/CU), bijective XCD swizzle (768 % 8 == 0).
// ---------------------------------------------------------------------------
__global__ __launch_bounds__(256, 3) void gemm_qkv(
    const unsigned short* __restrict__ Ah,
    const unsigned short* __restrict__ Bh,
    const float* __restrict__ bias,
    unsigned short* __restrict__ q_hi,
    unsigned short* __restrict__ kT,
    unsigned short* __restrict__ vTile,
    int N, int K) {
  // staging: A [128][64] bf16 (16 KB) | B [128][64] bf16 (16 KB) = 32 KB.
  // v-epilogue bounce reuses this as [128][132] ushort (33792 B).
  __shared__ char smraw[33792];
  const int tid  = threadIdx.x;
  const int wave = tid >> 6, lane = tid & 63;

  // bijective XCD swizzle: lin -> (lin%8)*96 + lin/8  (nwg=768, 768%8==0)
  const int lin = blockIdx.y * gridDim.x + blockIdx.x;
  const int swz = (lin & 7) * 96 + (lin >> 3);
  const int n0 = (swz % 24) * 128, m0 = (swz / 24) * 128;

  const int wm = (wave >> 1) * 64, wn = (wave & 1) * 64;
  const int quad = lane >> 4, ln16 = lane & 15;

  // ---- staging addresses: 32 insts total, 8 per wave -----------------------
  const bool isA = wave < 2;
  const unsigned short* src = isA ? Ah : Bh;
  const int baserow = isA ? m0 : n0;
  const int instbase = (wave & 1) * 8;
  const int dbase = (isA ? 0 : 16384) + instbase * 1024;  // bytes
  size_t goff[8];
#pragma unroll
  for (int i = 0; i < 8; ++i) {
    const int r = (instbase + i) * 8 + (lane >> 3);   // row within tile 0..127
    const int c = (lane & 7) ^ (r & 7);               // source k-chunk (involution)
    goff[i] = (size_t)(baserow + r) * K + c * 8;
  }

  // ---- ds_read offsets (bytes), chunk^=(r&7) swizzle, ks=1 is ^64 ---------
  int offA[4], offB[4];
#pragma unroll
  for (int t = 0; t < 4; ++t) {
    const int r = wm + t * 16 + ln16;
    offA[t] = r * 128 + ((quad ^ (r & 7)) * 16);
    const int rn = wn + t * 16 + ln16;
    offB[t] = 16384 + rn * 128 + ((quad ^ (rn & 7)) * 16);
  }

  f32x4 acc[4][4] = {};
  const char* smb = (const char*)smraw;

  for (int k0 = 0; k0 < K; k0 += 64) {
#pragma unroll
    for (int i = 0; i < 8; ++i)
      async_cp16(src + goff[i] + k0,
                 (unsigned short*)(smraw + dbase + i * 1024));
    __syncthreads();

    // ks = 0 (k 0..31)
    {
      short8 ah[4], bh[4];
#pragma unroll
      for (int t = 0; t < 4; ++t) {
        ah[t] = *(const short8*)(smb + offA[t]);
        bh[t] = *(const short8*)(smb + offB[t]);
      }
#pragma unroll
      for (int t = 0; t < 4; ++t)
#pragma unroll
        for (int u = 0; u < 4; ++u)
          acc[t][u] = __builtin_amdgcn_mfma_f32_16x16x32_bf16(bh[u], ah[t], acc[t][u], 0, 0, 0);
    }
    // ks = 1 (k 32..63): swizzled position differs by ^64 bytes
    {
      short8 ah[4], bh[4];
#pragma unroll
      for (int t = 0; t < 4; ++t) {
        ah[t] = *(const short8*)(smb + (offA[t] ^ 64));
        bh[t] = *(const short8*)(smb + (offB[t] ^ 64));
      }
#pragma unroll
      for (int t = 0; t < 4; ++t)
#pragma unroll
        for (int u = 0; u < 4; ++u)
          acc[t][u] = __builtin_amdgcn_mfma_f32_16x16x32_bf16(bh[u], ah[t], acc[t][u], 0, 0, 0);
    }
    __syncthreads();
  }

  // ---- epilogue. Swapped-D mapping: m = wm+t*16+ln16 ; n = wn+u*16+quad*4+e
  const int slot = n0 >> 10;       // block-uniform: 0=q, 1=k, 2=v
  const int nbase = n0 & 1023;

  if (slot == 0) {
#pragma unroll
    for (int t = 0; t < 4; ++t) {
      const int m = m0 + wm + t * 16 + ln16;
#pragma unroll
      for (int u = 0; u < 4; ++u) {
        const int nl = wn + u * 16 + quad * 4;
        const float4 bq = *(const float4*)&bias[n0 + nl];
        ushort4 h;
        h.x = f2bf(acc[t][u][0] + bq.x);
        h.y = f2bf(acc[t][u][1] + bq.y);
        h.z = f2bf(acc[t][u][2] + bq.z);
        h.w = f2bf(acc[t][u][3] + bq.w);
        *(ushort4*)&q_hi[(size_t)m * 1024 + nbase + nl] = h;
      }
    }
  } else if (slot == 1) {
#pragma unroll
    for (int t = 0; t < 4; ++t) {
      const int tok = m0 + wm + t * 16 + ln16;
      const int bb = tok >> 11, j = tok & 2047;
#pragma unroll
      for (int u = 0; u < 4; ++u) {
        const int nl = wn + u * 16 + quad * 4;
        const float4 bq = *(const float4*)&bias[n0 + nl];
        const int hd = nbase + nl;
        const int hh_ = hd >> 6, dg = (hd & 63) >> 3, di = hd & 7;
        ushort4 h;
        h.x = f2bf(acc[t][u][0] + bq.x);
        h.y = f2bf(acc[t][u][1] + bq.y);
        h.z = f2bf(acc[t][u][2] + bq.z);
        h.w = f2bf(acc[t][u][3] + bq.w);
        const size_t o =
            ((((size_t)bb * 16 + hh_) * 8 + dg) * 2048 + j) * 8 + di;
        *(ushort4*)&kT[o] = h;
      }
    }
  } else {
    // v: bounce through LDS [128 m][132] ushort, then coalesced 16-B stores
    unsigned short* lt = (unsigned short*)smraw;
#pragma unroll
    for (int t = 0; t < 4; ++t) {
      const int ml = wm + t * 16 + ln16;
#pragma unroll
      for (int u = 0; u < 4; ++u) {
        const int nl = wn + u * 16 + quad * 4;
        const float4 bq = *(const float4*)&bias[n0 + nl];
        ushort4 h;
        h.x = f2bf(acc[t][u][0] + bq.x);
        h.y = f2bf(acc[t][u][1] + bq.y);
        h.z = f2bf(acc[t][u][2] + bq.z);
        h.w = f2bf(acc[t][u][3] + bq.w);
        *(ushort4*)&lt[ml * 132 + nl] = h;
      }
    }
    __syncthreads();
    // 128 rows x 128 cols -> vTile[b][jg][col][8j]; 2048 chunks of 8 tokens
    const int jg0 = (m0 & 2047) >> 3;
    const int bb = m0 >> 11;
#pragma unroll
    for (int it = 0; it < 8; ++it) {
      const int chunk = it * 256 + tid;
      const int hd = chunk & 127, tokg = chunk >> 7;
      short8 hh;
#pragma unroll
      for (int s = 0; s < 8; ++s)
        hh[s] = (short)lt[(tokg * 8 + s) * 132 + hd];
      const size_t o =
          (((size_t)bb * 256 + jg0 + tokg) * 1024 + nbase + hd) * 8;
      *(short8*)&vTile[o] = hh;
    }
  }
}

// ---------------------------------------------------------------------------
// gemm_out: output projection, 128m x 64n tile, BK=64 (16 K-steps), 24 KB
// LDS, same chunk^=(r&7) zero-conflict swizzle and SWAPPED-operand epilogue
// as gemm_qkv.  fp32 C with float4 stores (4 consecutive n per lane).
// Grid 16x32 = 512 blocks (2/CU), bijective XCD swizzle (512 % 8 == 0).
// ---------------------------------------------------------------------------
__global__ __launch_bounds__(256, 2) void gemm_out(
    const unsigned short* __restrict__ Ah,   // attn_h [4096][1024] bf16
    const unsigned short* __restrict__ Bh,   // woutT  [1024 n][1024 k] bf16
    const float* __restrict__ bias,
    float* __restrict__ C,                   // [4096][1024] fp32
    int N, int K) {
  __shared__ char smraw[24576];  // A [128][64] (16 KB) | B [64][64] (8 KB)
  const int tid  = threadIdx.x;
  const int wave = tid >> 6, lane = tid & 63;

  // bijective XCD swizzle (nwg=512): lin -> (lin%8)*64 + lin/8
  const int lin = blockIdx.y * gridDim.x + blockIdx.x;
  const int swz = (lin & 7) * 64 + (lin >> 3);
  const int n0 = (swz % 16) * 64, m0 = (swz / 16) * 128;

  const int quad = lane >> 4, ln16 = lane & 15;
  const int wm = wave * 32;

  // ---- staging: 24 insts (A:16, B:8), 6 per wave ---------------------------
  const unsigned short* sptr[6];
  int dstoff[6];
#pragma unroll
  for (int s = 0; s < 6; ++s) {
    const int g = wave * 6 + s;
    const bool isA = g < 16;
    const unsigned short* base = isA ? Ah : Bh;
    const int r0 = isA ? g * 8 : (g - 16) * 8;
    const int r = r0 + (lane >> 3);
    const int c = (lane & 7) ^ (r & 7);     // involution swizzle
    sptr[s] = base + (size_t)((isA ? m0 : n0) + r) * K + c * 8;
    dstoff[s] = isA ? g * 1024 : 16384 + (g - 16) * 1024;
  }

  // ---- ds_read offsets (bytes); ks=1 is ^64 --------------------------------
  int offA[2], offB[4];
#pragma unroll
  for (int t = 0; t < 2; ++t) {
    const int r = wm + t * 16 + ln16;
    offA[t] = r * 128 + ((quad ^ (r & 7)) * 16);
  }
#pragma unroll
  for (int u = 0; u < 4; ++u) {
    const int rn = u * 16 + ln16;
    offB[u] = 16384 + rn * 128 + ((quad ^ (rn & 7)) * 16);
  }

  f32x4 acc[2][4] = {};
  const char* smb = (const char*)smraw;

  for (int k0 = 0; k0 < K; k0 += 64) {
#pragma unroll
    for (int s = 0; s < 6; ++s)
      async_cp16(sptr[s] + k0, (unsigned short*)(smraw + dstoff[s]));
    __syncthreads();

    // ks = 0
    {
      short8 ah[2], bh[4];
#pragma unroll
      for (int t = 0; t < 2; ++t) ah[t] = *(const short8*)(smb + offA[t]);
#pragma unroll
      for (int u = 0; u < 4; ++u) bh[u] = *(const short8*)(smb + offB[u]);
#pragma unroll
      for (int t = 0; t < 2; ++t)
#pragma unroll
        for (int u = 0; u < 4; ++u)
          acc[t][u] = __builtin_amdgcn_mfma_f32_16x16x32_bf16(bh[u], ah[t], acc[t][u], 0, 0, 0);
    }
    // ks = 1
    {
      short8 ah[2], bh[4];
#pragma unroll
      for (int t = 0; t < 2; ++t) ah[t] = *(const short8*)(smb + (offA[t] ^ 64));
#pragma unroll
      for (int u = 0; u < 4; ++u) bh[u] = *(const short8*)(smb + (offB[u] ^ 64));
#pragma unroll
      for (int t = 0; t < 2; ++t)
#pragma unroll
        for (int u = 0; u < 4; ++u)
          acc[t][u] = __builtin_amdgcn_mfma_f32_16x16x32_bf16(bh[u], ah[t], acc[t][u], 0, 0, 0);
    }
    __syncthreads();
  }

  // ---- epilogue: m = m0+wm+t*16+ln16 ; n = n0+u*16+quad*4+e ; float4 store
#pragma unroll
  for (int t = 0; t < 2; ++t) {
    const int m = m0 + wm + t * 16 + ln16;
#pragma unroll
    for (int u = 0; u < 4; ++u) {
      const int n = n0 + u * 16 + quad * 4;
      const float4 bq = *(const float4*)&bias[n];
      float4 o;
      o.x = acc[t][u][0] + bq.x;
      o.y = acc[t][u][1] + bq.y;
      o.z = acc[t][u][2] + bq.z;
      o.w = acc[t][u][3] + bq.w;
      *(float4*)&C[(size_t)m * N + n] = o;
    }
  }
}

// ---------------------------------------------------------------------------
// MFMA sliding-window attention (unchanged).
// ---------------------------------------------------------------------------
__global__ __launch_bounds__(256, 4) void attn_mfma(
    const unsigned short* __restrict__ q_hi,
    const unsigned short* __restrict__ kT,
    const unsigned short* __restrict__ vTile,
    unsigned short* __restrict__ attn_h) {
  __shared__ unsigned short P[TQ * PST];  // 18944 B (epilogue reuses as fp32)
  __shared__ float redS[2][32];

  const int b   = blockIdx.z;
  const int h   = blockIdx.y;
  const int i0  = blockIdx.x * TQ;
  const int tid = threadIdx.x;
  const int wave = tid >> 6, lane = tid & 63;
  const int quad = lane >> 4, ln16 = lane & 15;
  const int mt = wave >> 1, np = wave & 1;
  const int jlo = i0 - HALF_;
  const int rbase = mt * 16 + quad * 4;

  // ---- phase 1: scores -> exp -> P(bf16, unnormalized) + row sums --------
  float s[4] = {0.f, 0.f, 0.f, 0.f};
  {
    const size_t qbase =
        (size_t)(b * L_ + i0 + mt * 16 + ln16) * 1024 + h * 64 + quad * 8;
    const short8 qh0 = *(const short8*)&q_hi[qbase];
    const short8 qh1 = *(const short8*)&q_hi[qbase + 32];

    const size_t kb0 = (((size_t)b * 16 + h) * 8 + quad) * 2048 * 8;
    const size_t kb1 = (((size_t)b * 16 + h) * 8 + quad + 4) * 2048 * 8;

#pragma unroll
    for (int c = 0; c < 9; ++c) {
      const int nt   = np + 2 * c;
      const int jabs = jlo + nt * 16 + ln16;
      const int jcl  = min(max(jabs, 0), L_ - 1);
      const short8 kh0 = *(const short8*)&kT[kb0 + (size_t)jcl * 8];
      const short8 kh1 = *(const short8*)&kT[kb1 + (size_t)jcl * 8];

      f32x4 a = {};
      a = __builtin_amdgcn_mfma_f32_16x16x32_bf16(qh0, kh0, a, 0, 0, 0);
      a = __builtin_amdgcn_mfma_f32_16x16x32_bf16(qh1, kh1, a, 0, 0, 0);

      const int colj = nt * 16 + ln16;
#pragma unroll
      for (int e = 0; e < 4; ++e) {
        const int iabs = i0 + rbase + e;
        const bool ok = (jabs >= 0) && (jabs < L_) && (abs(iabs - jabs) <= HALF_);
        const float ev = ok ? __expf(a[e] * 0.125f) : 0.f;
        s[e] += ev;
        P[(rbase + e) * PST + colj] = f2bf(ev);
      }
    }
  }
#pragma unroll
  for (int e = 0; e < 4; ++e) {
    s[e] += __shfl_xor(s[e], 1);
    s[e] += __shfl_xor(s[e], 2);
    s[e] += __shfl_xor(s[e], 4);
    s[e] += __shfl_xor(s[e], 8);
  }
  if (ln16 == 0) {
#pragma unroll
    for (int e = 0; e < 4; ++e) redS[np][rbase + e] = s[e];
  }
  __syncthreads();
  float rinv[4];
#pragma unroll
  for (int e = 0; e < 4; ++e) rinv[e] = 1.f / (s[e] + redS[np ^ 1][rbase + e]);

  // ---- phase 2: O = P @ Vh (frag-tiled vTile, coalesced) ------------------
  f32x4 o[2] = {};
  {
    const int dp = np;
    const char* pb = (const char*)P;
#pragma unroll
    for (int c = 0; c < 9; ++c) {
      const short8 pf =
          *(const short8*)(pb + (mt * 16 + ln16) * (PST * 2) + c * 64 + quad * 16);
      int j0 = jlo + c * 32 + quad * 8;
      j0 = min(max(j0, 0), L_ - 8);
      const size_t jgbase = ((size_t)b * 256 + (j0 >> 3)) * 1024;
#pragma unroll
      for (int t = 0; t < 2; ++t) {
        const size_t vb = (jgbase + (h * 64 + dp * 32 + t * 16 + ln16)) * 8;
        const short8 vh = *(const short8*)&vTile[vb];
        o[t] = __builtin_amdgcn_mfma_f32_16x16x32_bf16(pf, vh, o[t], 0, 0, 0);
      }
    }
  }

  // ---- epilogue: normalize, LDS bounce, coalesced bf16 stores ------------
  __syncthreads();
  float* ob = (float*)P;
  {
    const int dp = np;
#pragma unroll
    for (int t = 0; t < 2; ++t)
#pragma unroll
      for (int e = 0; e < 4; ++e)
        ob[(rbase + e) * 68 + dp * 32 + t * 16 + ln16] = o[t][e] * rinv[e];
  }
  __syncthreads();
  {
    const int rr = tid >> 3, ck = tid & 7;
    const float* rp = ob + rr * 68 + ck * 8;
    const float4 f0 = *(const float4*)&rp[0];
    const float4 f1 = *(const float4*)&rp[4];
    short8 hh;
    hh[0] = (short)f2bf(f0.x); hh[1] = (short)f2bf(f0.y);
    hh[2] = (short)f2bf(f0.z); hh[3] = (short)f2bf(f0.w);
    hh[4] = (short)f2bf(f1.x); hh[5] = (short)f2bf(f1.y);
    hh[6] = (short)f2bf(f1.z); hh[7] = (short)f2bf(f1.w);
    const size_t oo = ((size_t)(b * L_ + i0 + rr)) * 1024 + h * 64 + ck * 8;
    *(short8*)&attn_h[oo] = hh;
  }
}

// ---------------------------------------------------------------------------
extern "C" void kernel_launch(void* const* d_in, const int* in_sizes, int n_in,
                              void* d_out, int out_size, void* d_ws, size_t ws_size,
                              hipStream_t stream) {
  const float* x     = (const float*)d_in[0];
  const float* w_qkv = (const float*)d_in[1];
  const float* b_qkv = (const float*)d_in[2];
  const float* w_out = (const float*)d_in[3];
  const float* b_out = (const float*)d_in[4];
  float* out = (float*)d_out;

  const int M = B_ * L_;  // 4096

  // workspace layout (bytes), total 48 MiB:
  //   x_hi @0 (8MiB)        [dead after QKV gemm; attn_h aliases it]
  //   wqkvT @16MiB (6MiB)
  //   woutT @22MiB (2MiB)
  //   q_hi  @24MiB (8MiB)   [B*L, 1024]
  //   kT    @32MiB (8MiB)   [b][h][dg8][j2048][8d]
  //   vTile @40MiB (8MiB)   [b][jg256][d1024][8j]
  char* ws = (char*)d_ws;
  unsigned short* x_hi    = (unsigned short*)(ws + 0);
  unsigned short* wqkvT   = (unsigned short*)(ws + 16777216);
  unsigned short* woutT   = (unsigned short*)(ws + 23068672);
  unsigned short* q_hi    = (unsigned short*)(ws + 25165824);
  unsigned short* kT      = (unsigned short*)(ws + 33554432);
  unsigned short* vTile   = (unsigned short*)(ws + 41943040);
  unsigned short* attn_hi = (unsigned short*)(ws + 0);

  // 1) fused prep: x round + both weight transposes
  prep<<<8192, 256, 0, stream>>>(x, x_hi, w_qkv, wqkvT, w_out, woutT);
  // 2) fused QKV projection (BK=64, swapped-operand epilogue) -> q_hi/kT/vTile
  {
    dim3 g(3072 / 128, M / 128);  // 24 x 32 = 768 blocks = 3/CU
    gemm_qkv<<<g, 256, 0, stream>>>(x_hi, wqkvT, b_qkv, q_hi, kT, vTile,
                                    3072, D_);
  }
  // 3) MFMA banded attention -> attn_h bf16 (aliases dead x_hi)
  {
    dim3 g(L_ / TQ, H_, B_);
    attn_mfma<<<g, 256, 0, stream>>>(q_hi, kT, vTile, attn_hi);
  }
  // 4) output projection (BK=64, swapped-operand, float4 stores) -> fp32 out
  {
    dim3 g(D_ / 64, M / 128);  // 16 x 32 = 512 blocks = 2/CU
    gemm_out<<<g, 256, 0, stream>>>(attn_hi, woutT, b_out, out, D_, D_);
  }
}

// Round 4
// 157.364 us; speedup vs baseline: 1.1571x; 1.0090x over previous
//
#include <hip/hip_runtime.h>
#include <math.h>

#define B_    2
#define L_    2048
#define D_    1024
#define H_    16
#define HD_   64
#define HALF_ 128

typedef __attribute__((ext_vector_type(8))) short short8;
typedef __attribute__((ext_vector_type(4))) float f32x4;

// ---- bf16 helpers (bitwise, RNE) -----------------------------------------
__device__ __forceinline__ unsigned short f2bf(float x) {
  unsigned int u = __float_as_uint(x);
  u = (u + 0x7fffu + ((u >> 16) & 1u)) >> 16;
  return (unsigned short)u;
}

__device__ __forceinline__ void async_cp16(const unsigned short* g, unsigned short* l) {
  __builtin_amdgcn_global_load_lds(
      (const __attribute__((address_space(1))) unsigned int*)g,
      (__attribute__((address_space(3))) unsigned int*)l, 16, 0, 0);
}

// ---------------------------------------------------------------------------
// prep: fused (a) x -> bf16 round (hi only), (b) w_qkv transpose+round,
//       (c) w_out transpose+round.
// ---------------------------------------------------------------------------
__device__ __forceinline__ void tr_round32(const float* __restrict__ in,
                                           unsigned short* __restrict__ hi,
                                           int N, int K, int n0, int k0,
                                           float (*t)[33], int tid) {
  {
    const int kl = tid >> 3, nl = (tid & 7) * 4;
    const float4 v = *(const float4*)&in[(size_t)(k0 + kl) * N + n0 + nl];
    t[kl][nl + 0] = v.x; t[kl][nl + 1] = v.y;
    t[kl][nl + 2] = v.z; t[kl][nl + 3] = v.w;
  }
  __syncthreads();
  {
    const int no = tid >> 3, ko = (tid & 7) * 4;
    ushort4 h;
    h.x = f2bf(t[ko + 0][no]);
    h.y = f2bf(t[ko + 1][no]);
    h.z = f2bf(t[ko + 2][no]);
    h.w = f2bf(t[ko + 3][no]);
    *(ushort4*)&hi[(size_t)(n0 + no) * K + k0 + ko] = h;
  }
}

__global__ __launch_bounds__(256) void prep(const float* __restrict__ x,
                                            unsigned short* __restrict__ x_hi,
                                            const float* __restrict__ w_qkv,
                                            unsigned short* __restrict__ wqkvT,
                                            const float* __restrict__ w_out,
                                            unsigned short* __restrict__ woutT) {
  __shared__ float t[32][33];
  const int bx = blockIdx.x, tid = threadIdx.x;
  if (bx < 4096) {
    const int i = (bx * 256 + tid) * 4;
    const float4 a = *(const float4*)&x[i];
    ushort4 h;
    h.x = f2bf(a.x); h.y = f2bf(a.y); h.z = f2bf(a.z); h.w = f2bf(a.w);
    *(ushort4*)&x_hi[i] = h;
  } else if (bx < 7168) {
    const int tb = bx - 4096;  // 96 x 32 tiles
    tr_round32(w_qkv, wqkvT, 3 * D_, D_, (tb % 96) * 32, (tb / 96) * 32, t, tid);
  } else {
    const int tb = bx - 7168;  // 32 x 32 tiles
    tr_round32(w_out, woutT, D_, D_, (tb % 32) * 32, (tb / 32) * 32, t, tid);
  }
}

// ---------------------------------------------------------------------------
// gemm_qkv: fused QKV projection, 128x128 tile, BK=64 (16 K-steps), 32 KB
// staging LDS, zero-conflict chunk^=(r&7) swizzle, swapped-operand epilogue.
// Grid: 768 blocks (3/CU), bijective XCD swizzle.  (unchanged from r2)
// ---------------------------------------------------------------------------
__global__ __launch_bounds__(256, 3) void gemm_qkv(
    const unsigned short* __restrict__ Ah,
    const unsigned short* __restrict__ Bh,
    const float* __restrict__ bias,
    unsigned short* __restrict__ q_hi,
    unsigned short* __restrict__ kT,
    unsigned short* __restrict__ vTile,
    int N, int K) {
  __shared__ char smraw[33792];
  const int tid  = threadIdx.x;
  const int wave = tid >> 6, lane = tid & 63;

  const int lin = blockIdx.y * gridDim.x + blockIdx.x;
  const int swz = (lin & 7) * 96 + (lin >> 3);
  const int n0 = (swz % 24) * 128, m0 = (swz / 24) * 128;

  const int wm = (wave >> 1) * 64, wn = (wave & 1) * 64;
  const int quad = lane >> 4, ln16 = lane & 15;

  const bool isA = wave < 2;
  const unsigned short* src = isA ? Ah : Bh;
  const int baserow = isA ? m0 : n0;
  const int instbase = (wave & 1) * 8;
  const int dbase = (isA ? 0 : 16384) + instbase * 1024;
  size_t goff[8];
#pragma unroll
  for (int i = 0; i < 8; ++i) {
    const int r = (instbase + i) * 8 + (lane >> 3);
    const int c = (lane & 7) ^ (r & 7);
    goff[i] = (size_t)(baserow + r) * K + c * 8;
  }

  int offA[4], offB[4];
#pragma unroll
  for (int t = 0; t < 4; ++t) {
    const int r = wm + t * 16 + ln16;
    offA[t] = r * 128 + ((quad ^ (r & 7)) * 16);
    const int rn = wn + t * 16 + ln16;
    offB[t] = 16384 + rn * 128 + ((quad ^ (rn & 7)) * 16);
  }

  f32x4 acc[4][4] = {};
  const char* smb = (const char*)smraw;

  for (int k0 = 0; k0 < K; k0 += 64) {
#pragma unroll
    for (int i = 0; i < 8; ++i)
      async_cp16(src + goff[i] + k0,
                 (unsigned short*)(smraw + dbase + i * 1024));
    __syncthreads();

    {
      short8 ah[4], bh[4];
#pragma unroll
      for (int t = 0; t < 4; ++t) {
        ah[t] = *(const short8*)(smb + offA[t]);
        bh[t] = *(const short8*)(smb + offB[t]);
      }
#pragma unroll
      for (int t = 0; t < 4; ++t)
#pragma unroll
        for (int u = 0; u < 4; ++u)
          acc[t][u] = __builtin_amdgcn_mfma_f32_16x16x32_bf16(bh[u], ah[t], acc[t][u], 0, 0, 0);
    }
    {
      short8 ah[4], bh[4];
#pragma unroll
      for (int t = 0; t < 4; ++t) {
        ah[t] = *(const short8*)(smb + (offA[t] ^ 64));
        bh[t] = *(const short8*)(smb + (offB[t] ^ 64));
      }
#pragma unroll
      for (int t = 0; t < 4; ++t)
#pragma unroll
        for (int u = 0; u < 4; ++u)
          acc[t][u] = __builtin_amdgcn_mfma_f32_16x16x32_bf16(bh[u], ah[t], acc[t][u], 0, 0, 0);
    }
    __syncthreads();
  }

  const int slot = n0 >> 10;
  const int nbase = n0 & 1023;

  if (slot == 0) {
#pragma unroll
    for (int t = 0; t < 4; ++t) {
      const int m = m0 + wm + t * 16 + ln16;
#pragma unroll
      for (int u = 0; u < 4; ++u) {
        const int nl = wn + u * 16 + quad * 4;
        const float4 bq = *(const float4*)&bias[n0 + nl];
        ushort4 h;
        h.x = f2bf(acc[t][u][0] + bq.x);
        h.y = f2bf(acc[t][u][1] + bq.y);
        h.z = f2bf(acc[t][u][2] + bq.z);
        h.w = f2bf(acc[t][u][3] + bq.w);
        *(ushort4*)&q_hi[(size_t)m * 1024 + nbase + nl] = h;
      }
    }
  } else if (slot == 1) {
#pragma unroll
    for (int t = 0; t < 4; ++t) {
      const int tok = m0 + wm + t * 16 + ln16;
      const int bb = tok >> 11, j = tok & 2047;
#pragma unroll
      for (int u = 0; u < 4; ++u) {
        const int nl = wn + u * 16 + quad * 4;
        const float4 bq = *(const float4*)&bias[n0 + nl];
        const int hd = nbase + nl;
        const int hh_ = hd >> 6, dg = (hd & 63) >> 3, di = hd & 7;
        ushort4 h;
        h.x = f2bf(acc[t][u][0] + bq.x);
        h.y = f2bf(acc[t][u][1] + bq.y);
        h.z = f2bf(acc[t][u][2] + bq.z);
        h.w = f2bf(acc[t][u][3] + bq.w);
        const size_t o =
            ((((size_t)bb * 16 + hh_) * 8 + dg) * 2048 + j) * 8 + di;
        *(ushort4*)&kT[o] = h;
      }
    }
  } else {
    unsigned short* lt = (unsigned short*)smraw;
#pragma unroll
    for (int t = 0; t < 4; ++t) {
      const int ml = wm + t * 16 + ln16;
#pragma unroll
      for (int u = 0; u < 4; ++u) {
        const int nl = wn + u * 16 + quad * 4;
        const float4 bq = *(const float4*)&bias[n0 + nl];
        ushort4 h;
        h.x = f2bf(acc[t][u][0] + bq.x);
        h.y = f2bf(acc[t][u][1] + bq.y);
        h.z = f2bf(acc[t][u][2] + bq.z);
        h.w = f2bf(acc[t][u][3] + bq.w);
        *(ushort4*)&lt[ml * 132 + nl] = h;
      }
    }
    __syncthreads();
    const int jg0 = (m0 & 2047) >> 3;
    const int bb = m0 >> 11;
#pragma unroll
    for (int it = 0; it < 8; ++it) {
      const int chunk = it * 256 + tid;
      const int hd = chunk & 127, tokg = chunk >> 7;
      short8 hh;
#pragma unroll
      for (int s = 0; s < 8; ++s)
        hh[s] = (short)lt[(tokg * 8 + s) * 132 + hd];
      const size_t o =
          (((size_t)bb * 256 + jg0 + tokg) * 1024 + nbase + hd) * 8;
      *(short8*)&vTile[o] = hh;
    }
  }
}

// ---------------------------------------------------------------------------
// gemm_out: output projection, 128m x 64n, BK=64, swapped-operand epilogue,
// float4 stores.  (unchanged from r3)
// ---------------------------------------------------------------------------
__global__ __launch_bounds__(256, 2) void gemm_out(
    const unsigned short* __restrict__ Ah,
    const unsigned short* __restrict__ Bh,
    const float* __restrict__ bias,
    float* __restrict__ C,
    int N, int K) {
  __shared__ char smraw[24576];
  const int tid  = threadIdx.x;
  const int wave = tid >> 6, lane = tid & 63;

  const int lin = blockIdx.y * gridDim.x + blockIdx.x;
  const int swz = (lin & 7) * 64 + (lin >> 3);
  const int n0 = (swz % 16) * 64, m0 = (swz / 16) * 128;

  const int quad = lane >> 4, ln16 = lane & 15;
  const int wm = wave * 32;

  const unsigned short* sptr[6];
  int dstoff[6];
#pragma unroll
  for (int s = 0; s < 6; ++s) {
    const int g = wave * 6 + s;
    const bool isA = g < 16;
    const unsigned short* base = isA ? Ah : Bh;
    const int r0 = isA ? g * 8 : (g - 16) * 8;
    const int r = r0 + (lane >> 3);
    const int c = (lane & 7) ^ (r & 7);
    sptr[s] = base + (size_t)((isA ? m0 : n0) + r) * K + c * 8;
    dstoff[s] = isA ? g * 1024 : 16384 + (g - 16) * 1024;
  }

  int offA[2], offB[4];
#pragma unroll
  for (int t = 0; t < 2; ++t) {
    const int r = wm + t * 16 + ln16;
    offA[t] = r * 128 + ((quad ^ (r & 7)) * 16);
  }
#pragma unroll
  for (int u = 0; u < 4; ++u) {
    const int rn = u * 16 + ln16;
    offB[u] = 16384 + rn * 128 + ((quad ^ (rn & 7)) * 16);
  }

  f32x4 acc[2][4] = {};
  const char* smb = (const char*)smraw;

  for (int k0 = 0; k0 < K; k0 += 64) {
#pragma unroll
    for (int s = 0; s < 6; ++s)
      async_cp16(sptr[s] + k0, (unsigned short*)(smraw + dstoff[s]));
    __syncthreads();

    {
      short8 ah[2], bh[4];
#pragma unroll
      for (int t = 0; t < 2; ++t) ah[t] = *(const short8*)(smb + offA[t]);
#pragma unroll
      for (int u = 0; u < 4; ++u) bh[u] = *(const short8*)(smb + offB[u]);
#pragma unroll
      for (int t = 0; t < 2; ++t)
#pragma unroll
        for (int u = 0; u < 4; ++u)
          acc[t][u] = __builtin_amdgcn_mfma_f32_16x16x32_bf16(bh[u], ah[t], acc[t][u], 0, 0, 0);
    }
    {
      short8 ah[2], bh[4];
#pragma unroll
      for (int t = 0; t < 2; ++t) ah[t] = *(const short8*)(smb + (offA[t] ^ 64));
#pragma unroll
      for (int u = 0; u < 4; ++u) bh[u] = *(const short8*)(smb + (offB[u] ^ 64));
#pragma unroll
      for (int t = 0; t < 2; ++t)
#pragma unroll
        for (int u = 0; u < 4; ++u)
          acc[t][u] = __builtin_amdgcn_mfma_f32_16x16x32_bf16(bh[u], ah[t], acc[t][u], 0, 0, 0);
    }
    __syncthreads();
  }

#pragma unroll
  for (int t = 0; t < 2; ++t) {
    const int m = m0 + wm + t * 16 + ln16;
#pragma unroll
    for (int u = 0; u < 4; ++u) {
      const int n = n0 + u * 16 + quad * 4;
      const float4 bq = *(const float4*)&bias[n];
      float4 o;
      o.x = acc[t][u][0] + bq.x;
      o.y = acc[t][u][1] + bq.y;
      o.z = acc[t][u][2] + bq.z;
      o.w = acc[t][u][3] + bq.w;
      *(float4*)&C[(size_t)m * N + n] = o;
    }
  }
}

// ---------------------------------------------------------------------------
// attn_mfma v2: swapped-operand QK^T -> P lives in registers (q = ln16,
// j lane-local).  Row sums finish with 2 shfl_xor (no LDS).  P reaches PV's
// A-fragment via 8 shfl + 4 selects per 32-token slab (quad redistribution).
// TQ=64 per block, 4 waves (one 16-q subtile each), 10 slabs of 32 tokens.
// No P slab, no mid-kernel barriers; single barrier before the store bounce.
// Layouts of q_hi / kT / vTile / attn_h unchanged.
// ---------------------------------------------------------------------------
__global__ __launch_bounds__(256) void attn_mfma(
    const unsigned short* __restrict__ q_hi,
    const unsigned short* __restrict__ kT,
    const unsigned short* __restrict__ vTile,
    unsigned short* __restrict__ attn_h) {
  __shared__ float ob[64 * 68];  // 17408 B

  const int b   = blockIdx.z;
  const int h   = blockIdx.y;
  const int i0  = blockIdx.x * 64;
  const int tid = threadIdx.x;
  const int mt  = tid >> 6, lane = tid & 63;
  const int quad = lane >> 4, ln16 = lane & 15;
  const int jlo = i0 - HALF_;

  // Q as B-frag: lane holds Q[q = mt*16+ln16][d = quad*8 + i (+32)]
  const size_t qbase =
      (size_t)(b * L_ + i0 + mt * 16 + ln16) * 1024 + h * 64 + quad * 8;
  const short8 qh0 = *(const short8*)&q_hi[qbase];
  const short8 qh1 = *(const short8*)&q_hi[qbase + 32];

  // kT bases: dg = quad (d 0..31) and quad+4 (d 32..63)
  const size_t kb0 = (((size_t)b * 16 + h) * 8 + quad) * 2048 * 8;
  const size_t kb1 = (((size_t)b * 16 + h) * 8 + quad + 4) * 2048 * 8;

  const int iabs = i0 + mt * 16 + ln16;  // this lane's q row (mask)

  f32x4 o[4] = {};
  float s = 0.f;

#pragma unroll
  for (int c = 0; c < 10; ++c) {
    const int base = jlo + c * 32;

    // ---- K loads: A-frag rows j = base + ch*16 + ln16 (clamped; masked) --
    const int j0c = min(max(base + ln16, 0), L_ - 1);
    const int j1c = min(max(base + 16 + ln16, 0), L_ - 1);
    const short8 k00 = *(const short8*)&kT[kb0 + (size_t)j0c * 8];
    const short8 k01 = *(const short8*)&kT[kb1 + (size_t)j0c * 8];
    const short8 k10 = *(const short8*)&kT[kb0 + (size_t)j1c * 8];
    const short8 k11 = *(const short8*)&kT[kb1 + (size_t)j1c * 8];

    // ---- V loads: B-frag V[j = base + quad*8 + i][d = t*16 + ln16] -------
    const int jv = min(max(base + quad * 8, 0), L_ - 8);
    const size_t vgb = ((size_t)b * 256 + (jv >> 3)) * 1024 + h * 64;
    short8 vh[4];
#pragma unroll
    for (int t = 0; t < 4; ++t)
      vh[t] = *(const short8*)&vTile[(vgb + t * 16 + ln16) * 8];

    // ---- swapped QK^T: D[j-off = quad*4+e][q = ln16] ---------------------
    f32x4 a0 = {}, a1 = {};
    a0 = __builtin_amdgcn_mfma_f32_16x16x32_bf16(k00, qh0, a0, 0, 0, 0);
    a0 = __builtin_amdgcn_mfma_f32_16x16x32_bf16(k01, qh1, a0, 0, 0, 0);
    a1 = __builtin_amdgcn_mfma_f32_16x16x32_bf16(k10, qh0, a1, 0, 0, 0);
    a1 = __builtin_amdgcn_mfma_f32_16x16x32_bf16(k11, qh1, a1, 0, 0, 0);

    // ---- mask + exp + bf16 pack (chunk0 = pk0x, chunk1 = pk1x) -----------
    unsigned int pk00, pk01, pk10, pk11;
    {
      float ev[4];
#pragma unroll
      for (int e = 0; e < 4; ++e) {
        const int jabs = base + quad * 4 + e;
        const bool ok = (jabs >= 0) && (jabs < L_) && (abs(iabs - jabs) <= HALF_);
        ev[e] = ok ? __expf(a0[e] * 0.125f) : 0.f;
        s += ev[e];
      }
      pk00 = (unsigned)f2bf(ev[0]) | ((unsigned)f2bf(ev[1]) << 16);
      pk01 = (unsigned)f2bf(ev[2]) | ((unsigned)f2bf(ev[3]) << 16);
    }
    {
      float ev[4];
#pragma unroll
      for (int e = 0; e < 4; ++e) {
        const int jabs = base + 16 + quad * 4 + e;
        const bool ok = (jabs >= 0) && (jabs < L_) && (abs(iabs - jabs) <= HALF_);
        ev[e] = ok ? __expf(a1[e] * 0.125f) : 0.f;
        s += ev[e];
      }
      pk10 = (unsigned)f2bf(ev[0]) | ((unsigned)f2bf(ev[1]) << 16);
      pk11 = (unsigned)f2bf(ev[2]) | ((unsigned)f2bf(ev[3]) << 16);
    }

    // ---- assemble P A-frag: pf[i] = P[q=ln16][base + quad*8 + i] ---------
    // target quad q, regs 0-3 from src quad (q&1)*2, regs 4-7 from +1;
    // chunk word selected by q>>1.
    const int src0 = ((quad & 1) * 2) * 16 + ln16;
    const int src1 = src0 + 16;
    const unsigned a0w = (unsigned)__shfl((int)pk00, src0);
    const unsigned b0w = (unsigned)__shfl((int)pk10, src0);
    const unsigned a1w = (unsigned)__shfl((int)pk01, src0);
    const unsigned b1w = (unsigned)__shfl((int)pk11, src0);
    const unsigned a2w = (unsigned)__shfl((int)pk00, src1);
    const unsigned b2w = (unsigned)__shfl((int)pk10, src1);
    const unsigned a3w = (unsigned)__shfl((int)pk01, src1);
    const unsigned b3w = (unsigned)__shfl((int)pk11, src1);
    int4 wv;
    wv.x = (int)((quad < 2) ? a0w : b0w);
    wv.y = (int)((quad < 2) ? a1w : b1w);
    wv.z = (int)((quad < 2) ? a2w : b2w);
    wv.w = (int)((quad < 2) ? a3w : b3w);
    const short8 pf = *(const short8*)&wv;

    // ---- PV: O[q = quad*4+e][d = t*16+ln16] ------------------------------
#pragma unroll
    for (int t = 0; t < 4; ++t)
      o[t] = __builtin_amdgcn_mfma_f32_16x16x32_bf16(pf, vh[t], o[t], 0, 0, 0);
  }

  // ---- finish row sums (q = ln16) and fetch rinv for rows quad*4+e -------
  s += __shfl_xor(s, 16);
  s += __shfl_xor(s, 32);
  float rinv[4];
#pragma unroll
  for (int e = 0; e < 4; ++e)
    rinv[e] = 1.f / __shfl(s, quad * 4 + e);

  // ---- epilogue: normalize, LDS bounce, coalesced bf16 stores ------------
#pragma unroll
  for (int t = 0; t < 4; ++t)
#pragma unroll
    for (int e = 0; e < 4; ++e)
      ob[(mt * 16 + quad * 4 + e) * 68 + t * 16 + ln16] = o[t][e] * rinv[e];
  __syncthreads();
#pragma unroll
  for (int pass = 0; pass < 2; ++pass) {
    const int rr = pass * 32 + (tid >> 3), ck = tid & 7;
    const float* rp = &ob[rr * 68 + ck * 8];
    const float4 f0 = *(const float4*)&rp[0];
    const float4 f1 = *(const float4*)&rp[4];
    short8 hh;
    hh[0] = (short)f2bf(f0.x); hh[1] = (short)f2bf(f0.y);
    hh[2] = (short)f2bf(f0.z); hh[3] = (short)f2bf(f0.w);
    hh[4] = (short)f2bf(f1.x); hh[5] = (short)f2bf(f1.y);
    hh[6] = (short)f2bf(f1.z); hh[7] = (short)f2bf(f1.w);
    const size_t oo = ((size_t)(b * L_ + i0 + rr)) * 1024 + h * 64 + ck * 8;
    *(short8*)&attn_h[oo] = hh;
  }
}

// ---------------------------------------------------------------------------
extern "C" void kernel_launch(void* const* d_in, const int* in_sizes, int n_in,
                              void* d_out, int out_size, void* d_ws, size_t ws_size,
                              hipStream_t stream) {
  const float* x     = (const float*)d_in[0];
  const float* w_qkv = (const float*)d_in[1];
  const float* b_qkv = (const float*)d_in[2];
  const float* w_out = (const float*)d_in[3];
  const float* b_out = (const float*)d_in[4];
  float* out = (float*)d_out;

  const int M = B_ * L_;  // 4096

  // workspace layout (bytes), total 48 MiB:
  //   x_hi @0 (8MiB)        [dead after QKV gemm; attn_h aliases it]
  //   wqkvT @16MiB (6MiB)
  //   woutT @22MiB (2MiB)
  //   q_hi  @24MiB (8MiB)   [B*L, 1024]
  //   kT    @32MiB (8MiB)   [b][h][dg8][j2048][8d]
  //   vTile @40MiB (8MiB)   [b][jg256][d1024][8j]
  char* ws = (char*)d_ws;
  unsigned short* x_hi    = (unsigned short*)(ws + 0);
  unsigned short* wqkvT   = (unsigned short*)(ws + 16777216);
  unsigned short* woutT   = (unsigned short*)(ws + 23068672);
  unsigned short* q_hi    = (unsigned short*)(ws + 25165824);
  unsigned short* kT      = (unsigned short*)(ws + 33554432);
  unsigned short* vTile   = (unsigned short*)(ws + 41943040);
  unsigned short* attn_hi = (unsigned short*)(ws + 0);

  // 1) fused prep: x round + both weight transposes
  prep<<<8192, 256, 0, stream>>>(x, x_hi, w_qkv, wqkvT, w_out, woutT);
  // 2) fused QKV projection -> q_hi / kT / vTile
  {
    dim3 g(3072 / 128, M / 128);  // 768 blocks = 3/CU
    gemm_qkv<<<g, 256, 0, stream>>>(x_hi, wqkvT, b_qkv, q_hi, kT, vTile,
                                    3072, D_);
  }
  // 3) banded attention v2 (TQ=64, in-register P) -> attn_h bf16
  {
    dim3 g(L_ / 64, H_, B_);  // 32 x 16 x 2 = 1024 blocks
    attn_mfma<<<g, 256, 0, stream>>>(q_hi, kT, vTile, attn_hi);
  }
  // 4) output projection -> fp32 d_out
  {
    dim3 g(D_ / 64, M / 128);  // 512 blocks
    gemm_out<<<g, 256, 0, stream>>>(attn_hi, woutT, b_out, out, D_, D_);
  }
}